// Round 1
// baseline (2110.931 us; speedup 1.0000x reference)
//
#include <hip/hip_runtime.h>
#include <hip/hip_bf16.h>

#define N_NODES 20000
#define N_EDGES 8000
#define DIM 128

typedef __attribute__((ext_vector_type(8))) short bf16x8;
typedef __attribute__((ext_vector_type(4))) short short4v;
typedef __attribute__((ext_vector_type(4))) float floatx4;

// fp32 -> bf16 (RNE), returns raw bits
__device__ __forceinline__ short f2bf(float x) {
    unsigned u = __builtin_bit_cast(unsigned, x);
    unsigned r = (u + 0x7fffu + ((u >> 16) & 1u)) >> 16;
    return (short)r;
}

// ---------------------------------------------------------------------------
// Unified MFMA GEMM: C[M x 128] = A[M x K] * B[K x 128]
//   A: fp32 global.  TRANS_A=false: A row-major [m][k], leading dim lda.
//                    TRANS_A=true : A stored [k][m] (i.e. A[m][k]=Ag[k*lda+m]).
//   B: bf16 global, row-major [k][n], n = 128.
//   EPI=0: atomicAdd fp32 into Cacc (split-K)
//   EPI=1: out = bf16( (acc + bias[col]) * rowscale[row] ) -> Obf
// Tile: BM=128, BN=128, BK=64; 4 waves, each 64x64 (4x4 frags of 16x16x32).
// ---------------------------------------------------------------------------
template<bool TRANS_A, int EPI>
__global__ __launch_bounds__(256, 2)
void gemm_kernel(const float* __restrict__ A,
                 const __hip_bfloat16* __restrict__ B,
                 float* __restrict__ Cacc,
                 __hip_bfloat16* __restrict__ Obf,
                 const float* __restrict__ bias,
                 const float* __restrict__ rowscale,
                 int M, int K, int lda, int MT, int kchunk)
{
    constexpr int SK = 72;                 // padded k-stride (144B, 16B-aligned)
    __shared__ short As[128 * SK];
    __shared__ short Bs[128 * SK];

    const int mt = blockIdx.x % MT;
    const int ks = blockIdx.x / MT;
    const int m0 = mt * 128;
    long kbeg = (long)ks * kchunk;
    long kend = kbeg + kchunk; if (kend > K) kend = (long)K;

    const int tid  = threadIdx.x;
    const int lane = tid & 63;
    const int wave = tid >> 6;
    const int wm = (wave & 1) * 64;
    const int wn = (wave >> 1) * 64;
    const int l15 = lane & 15;
    const int lq  = lane >> 4;

    floatx4 zero4 = {0.f, 0.f, 0.f, 0.f};
    floatx4 acc[4][4];
    #pragma unroll
    for (int i = 0; i < 4; i++)
        #pragma unroll
        for (int j = 0; j < 4; j++) acc[i][j] = zero4;

    for (long k0 = kbeg; k0 < kend; k0 += 64) {
        const int klen = (int)((kend - k0) < 64 ? (kend - k0) : 64);

        // ---- stage A tile -> As[m][k] (bf16) ----
        if (!TRANS_A) {
            const int r = tid >> 4;          // 0..15
            const int c = (tid & 15) * 4;    // 0..60
            #pragma unroll
            for (int p = 0; p < 8; p++) {
                const int row = p * 16 + r;
                const int gm  = m0 + row;
                float4 v = make_float4(0.f, 0.f, 0.f, 0.f);
                if (gm < M && c < klen)
                    v = *(const float4*)(A + (long)gm * lda + k0 + c);
                short4v s;
                s[0] = f2bf(v.x); s[1] = f2bf(v.y); s[2] = f2bf(v.z); s[3] = f2bf(v.w);
                *(short4v*)(&As[row * SK + c]) = s;
            }
        } else {
            // global rows are k, columns are m (contiguous) -> transpose into LDS
            const int r = tid >> 5;          // 0..7
            const int c = (tid & 31) * 4;    // 0..124
            #pragma unroll
            for (int p = 0; p < 8; p++) {
                const int krow = p * 8 + r;  // 0..63
                const int gm   = m0 + c;
                float4 v = make_float4(0.f, 0.f, 0.f, 0.f);
                if (krow < klen && gm < M)
                    v = *(const float4*)(A + (k0 + krow) * (long)lda + gm);
                As[(c + 0) * SK + krow] = f2bf(v.x);
                As[(c + 1) * SK + krow] = f2bf(v.y);
                As[(c + 2) * SK + krow] = f2bf(v.z);
                As[(c + 3) * SK + krow] = f2bf(v.w);
            }
        }

        // ---- stage B tile -> Bs[n][k] (transpose) ----
        {
            const int rb = tid >> 4;         // 0..15
            const int cb = (tid & 15) * 8;   // 0..120
            #pragma unroll
            for (int p = 0; p < 4; p++) {
                const int krow = p * 16 + rb;
                bf16x8 v = {0, 0, 0, 0, 0, 0, 0, 0};
                if (krow < klen)
                    v = *(const bf16x8*)(B + (long)(k0 + krow) * 128 + cb);
                #pragma unroll
                for (int i = 0; i < 8; i++)
                    Bs[(cb + i) * SK + krow] = v[i];
            }
        }
        __syncthreads();

        // ---- MFMA inner loop ----
        #pragma unroll
        for (int kk = 0; kk < 64; kk += 32) {
            bf16x8 af[4], bfr[4];
            #pragma unroll
            for (int i = 0; i < 4; i++) {
                af[i]  = *(const bf16x8*)(&As[(wm + i * 16 + l15) * SK + kk + lq * 8]);
                bfr[i] = *(const bf16x8*)(&Bs[(wn + i * 16 + l15) * SK + kk + lq * 8]);
            }
            #pragma unroll
            for (int i = 0; i < 4; i++)
                #pragma unroll
                for (int j = 0; j < 4; j++)
                    acc[i][j] = __builtin_amdgcn_mfma_f32_16x16x32_bf16(
                        af[i], bfr[j], acc[i][j], 0, 0, 0);
        }
        __syncthreads();
    }

    // ---- epilogue ----
    #pragma unroll
    for (int i = 0; i < 4; i++) {
        #pragma unroll
        for (int j = 0; j < 4; j++) {
            const int col = wn + j * 16 + l15;
            #pragma unroll
            for (int r = 0; r < 4; r++) {
                const int row = m0 + wm + i * 16 + lq * 4 + r;
                if (row < M) {
                    if (EPI == 0) {
                        atomicAdd(Cacc + (long)row * 128 + col, acc[i][j][r]);
                    } else {
                        float v = (acc[i][j][r] + bias[col]) * rowscale[row];
                        Obf[(long)row * 128 + col] = __float2bfloat16(v);
                    }
                }
            }
        }
    }
}

// ---------------------------------------------------------------------------
// X0[n][d] = emb[n] . Wt[type_ids[n]][:,d] + bt[type_ids[n]][d]
// one block (128 threads) per node; Wt (320 KB) stays L2-resident
// ---------------------------------------------------------------------------
__global__ void x0_kernel(const float* __restrict__ emb, const float* __restrict__ Wt,
                          const float* __restrict__ bt, const int* __restrict__ tids,
                          float* __restrict__ X0)
{
    const int n = blockIdx.x;
    const int d = threadIdx.x;
    __shared__ float er[128];
    er[d] = emb[(long)n * 128 + d];
    __syncthreads();
    const int t = tids[n];
    const float* W = Wt + (long)t * 128 * 128;
    float acc = bt[t * 128 + d];
    #pragma unroll 8
    for (int k = 0; k < 128; k++)
        acc = fmaf(er[k], W[k * 128 + d], acc);
    X0[(long)n * 128 + d] = acc;
}

__global__ void prep_kernel(const float* __restrict__ W1, const float* __restrict__ W2,
                            const float* __restrict__ fw,
                            __hip_bfloat16* __restrict__ W1b, __hip_bfloat16* __restrict__ W2b,
                            float* __restrict__ w)
{
    int i = blockIdx.x * 256 + threadIdx.x;
    if (i < 16384) {
        W1b[i] = __float2bfloat16(W1[i]);
        W2b[i] = __float2bfloat16(W2[i]);
    }
    if (i == 0) {
        float a = fw[0], b = fw[1], c = fw[2];
        float m = fmaxf(a, fmaxf(b, c));
        float ea = __expf(a - m), eb = __expf(b - m), ec = __expf(c - m);
        float s = ea + eb + ec;
        w[0] = ea / s; w[1] = eb / s; w[2] = ec / s;
    }
}

__global__ void mscale_kernel(const float* __restrict__ Cm, const float* __restrict__ de,
                              __hip_bfloat16* __restrict__ mb, int total)
{
    int i = blockIdx.x * 256 + threadIdx.x;
    if (i < total) mb[i] = __float2bfloat16(de[i >> 7] * Cm[i]);
}

__global__ void rowscale_kernel(const float* __restrict__ C, const float* __restrict__ dv,
                                float* __restrict__ X, int total)
{
    int i = blockIdx.x * 256 + threadIdx.x;
    if (i < total) X[i] = dv[i >> 7] * C[i];
}

__global__ void fusion_kernel(const float* __restrict__ X0, const float* __restrict__ X1,
                              const float* __restrict__ C2, const float* __restrict__ dv,
                              const float* __restrict__ w, float* __restrict__ out, int total)
{
    int i = blockIdx.x * 256 + threadIdx.x;
    if (i < total)
        out[i] = w[0] * X0[i] + w[1] * X1[i] + w[2] * (dv[i >> 7] * C2[i]);
}

// ---------------------------------------------------------------------------
extern "C" void kernel_launch(void* const* d_in, const int* in_sizes, int n_in,
                              void* d_out, int out_size, void* d_ws, size_t ws_size,
                              hipStream_t stream)
{
    const float* emb = (const float*)d_in[0];
    const float* Wt  = (const float*)d_in[1];
    const float* bt  = (const float*)d_in[2];
    const float* W1  = (const float*)d_in[3];
    const float* b1  = (const float*)d_in[4];
    const float* W2  = (const float*)d_in[5];
    const float* b2  = (const float*)d_in[6];
    const float* fw  = (const float*)d_in[7];
    const float* H   = (const float*)d_in[8];
    const float* dv  = (const float*)d_in[9];
    const float* de  = (const float*)d_in[10];
    const int*   tids= (const int*)d_in[11];
    float* out = (float*)d_out;

    const long ND = (long)N_NODES * DIM;   // 2,560,000
    const long ED = (long)N_EDGES * DIM;   // 1,024,000

    float* X0 = (float*)d_ws;
    float* X1 = X0 + ND;
    float* C2 = X1 + ND;
    float* Cm = C2 + ND;
    float* w  = Cm + ED;
    __hip_bfloat16* Y   = (__hip_bfloat16*)(w + 4);
    __hip_bfloat16* mb  = Y + ND;
    __hip_bfloat16* W1b = mb + ED;
    __hip_bfloat16* W2b = W1b + 16384;
    size_t need = (size_t)((char*)(W2b + 16384) - (char*)d_ws);
    if (ws_size < need) return;  // workspace too small; fail loudly instead of corrupting

    prep_kernel<<<64, 256, 0, stream>>>(W1, W2, fw, W1b, W2b, w);
    x0_kernel<<<N_NODES, 128, 0, stream>>>(emb, Wt, bt, tids, X0);

    // ---------------- layer 1 ----------------
    // Y = bf16( dv * (X0 @ W1 + b1) )
    gemm_kernel<false, 1><<<157, 256, 0, stream>>>(
        X0, W1b, nullptr, Y, b1, dv, N_NODES, 128, 128, 157, 128);
    // Cm = H^T @ Y  (M=E, K=N, split-K 8)
    hipMemsetAsync(Cm, 0, (size_t)ED * 4, stream);
    gemm_kernel<true, 0><<<63 * 8, 256, 0, stream>>>(
        H, Y, Cm, nullptr, nullptr, nullptr, N_EDGES, N_NODES, N_EDGES, 63, 2560);
    // mb = bf16(de * Cm)
    mscale_kernel<<<(int)(ED / 256), 256, 0, stream>>>(Cm, de, mb, (int)ED);
    // C2 = H @ mb  (M=N, K=E, split-K 4)
    hipMemsetAsync(C2, 0, (size_t)ND * 4, stream);
    gemm_kernel<false, 0><<<157 * 4, 256, 0, stream>>>(
        H, mb, C2, nullptr, nullptr, nullptr, N_NODES, N_EDGES, N_EDGES, 157, 2048);
    // X1 = dv * C2
    rowscale_kernel<<<(int)(ND / 256), 256, 0, stream>>>(C2, dv, X1, (int)ND);

    // ---------------- layer 2 ----------------
    gemm_kernel<false, 1><<<157, 256, 0, stream>>>(
        X1, W2b, nullptr, Y, b2, dv, N_NODES, 128, 128, 157, 128);
    hipMemsetAsync(Cm, 0, (size_t)ED * 4, stream);
    gemm_kernel<true, 0><<<63 * 8, 256, 0, stream>>>(
        H, Y, Cm, nullptr, nullptr, nullptr, N_EDGES, N_NODES, N_EDGES, 63, 2560);
    mscale_kernel<<<(int)(ED / 256), 256, 0, stream>>>(Cm, de, mb, (int)ED);
    hipMemsetAsync(C2, 0, (size_t)ND * 4, stream);
    gemm_kernel<false, 0><<<157 * 4, 256, 0, stream>>>(
        H, mb, C2, nullptr, nullptr, nullptr, N_NODES, N_EDGES, N_EDGES, 157, 2048);

    // out = w0*X0 + w1*X1 + w2*(dv*C2)
    fusion_kernel<<<(int)(ND / 256), 256, 0, stream>>>(X0, X1, C2, dv, w, out, (int)ND);
}

// Round 2
// 1488.885 us; speedup vs baseline: 1.4178x; 1.4178x over previous
//
#include <hip/hip_runtime.h>
#include <hip/hip_bf16.h>

#define NN 20000
#define NE 8000
#define DD 128

typedef __attribute__((ext_vector_type(8))) short bf16x8;
typedef __attribute__((ext_vector_type(4))) short short4v;
typedef __attribute__((ext_vector_type(4))) float floatx4;

// fp32 -> bf16 (RNE), raw bits
__device__ __forceinline__ short f2bf(float x) {
    unsigned u = __builtin_bit_cast(unsigned, x);
    unsigned r = (u + 0x7fffu + ((u >> 16) & 1u)) >> 16;
    return (short)r;
}

// async global->LDS, 16B per lane. LDS dest must be wave-uniform base + lane*16.
__device__ __forceinline__ void load16_lds(const void* gptr, void* lptr) {
    __builtin_amdgcn_global_load_lds(
        (const __attribute__((address_space(1))) unsigned int*)(unsigned long long)(uintptr_t)gptr,
        (__attribute__((address_space(3))) unsigned int*)(unsigned int)(uintptr_t)lptr,
        16, 0, 0);
}

// ---------------------------------------------------------------------------
// C[M x 128] = A[M x K] @ B[K x 128], A bf16 row-major [m][k], Bt bf16 [n][k].
// EPI=0: store fp32 partial to Cpart + ks*M*128 (split-K, reduced later)
// EPI=1: Ot[n][m] = bf16((acc + bias[n]) * rowscale[m])   (transposed bf16 out)
// Tile 128x128, BK=64; 4 waves of 64x64; all staging via global_load_lds.
// A rows may be read up to 95 rows past M (caller guarantees mapped memory).
// ---------------------------------------------------------------------------
template<int EPI>
__global__ __launch_bounds__(256, 2)
void gemm_bt(const short* __restrict__ A, const short* __restrict__ Bt,
             float* __restrict__ Cpart, short* __restrict__ Ot,
             const float* __restrict__ bias, const float* __restrict__ rowscale,
             int M, int K, int MT, int kchunk)
{
    __shared__ short As[128 * 64];
    __shared__ short Bs[128 * 64];

    const int mt = blockIdx.x % MT;
    const int ks = blockIdx.x / MT;
    const int m0 = mt * 128;
    long kbeg = (long)ks * kchunk;
    long kend = kbeg + kchunk; if (kend > K) kend = K;

    const int tid  = threadIdx.x;
    const int lane = tid & 63;
    const int wave = tid >> 6;
    const int wm = (wave & 1) * 64;
    const int wn = (wave >> 1) * 64;
    const int l15 = lane & 15;
    const int lq  = lane >> 4;
    const int sm = lane >> 3;          // staging: row within 8-row chunk
    const int sk = (lane & 7) * 8;     // staging: k element offset

    floatx4 acc[4][4];
    #pragma unroll
    for (int i = 0; i < 4; i++)
        #pragma unroll
        for (int j = 0; j < 4; j++) acc[i][j] = (floatx4){0.f, 0.f, 0.f, 0.f};

    for (long k0 = kbeg; k0 < kend; k0 += 64) {
        const int klen = (int)((kend - k0) < 64 ? (kend - k0) : 64);
        if (klen == 64) {
            #pragma unroll
            for (int p = 0; p < 4; p++) {
                const int chunk = wave * 4 + p;      // 0..15
                const int m = chunk * 8 + sm;
                load16_lds(A + (long)(m0 + m) * K + k0 + sk, &As[m * 64 + sk]);
            }
            #pragma unroll
            for (int p = 0; p < 4; p++) {
                const int chunk = wave * 4 + p;
                const int n = chunk * 8 + sm;
                load16_lds(Bt + (long)n * K + k0 + sk, &Bs[n * 64 + sk]);
            }
        } else {
            // K-tail (klen multiple of 8): masked VALU staging, zero-fill rest
            const int row = tid >> 1, kh = (tid & 1) * 32;
            #pragma unroll
            for (int c = 0; c < 4; c++) {
                const int k = kh + c * 8;
                bf16x8 va = {0,0,0,0,0,0,0,0}, vb = {0,0,0,0,0,0,0,0};
                if (k < klen) {
                    va = *(const bf16x8*)(A  + (long)(m0 + row) * K + k0 + k);
                    vb = *(const bf16x8*)(Bt + (long)row * K + k0 + k);
                }
                *(bf16x8*)&As[row * 64 + k] = va;
                *(bf16x8*)&Bs[row * 64 + k] = vb;
            }
        }
        __syncthreads();

        #pragma unroll
        for (int kk = 0; kk < 64; kk += 32) {
            bf16x8 af[4], bf_[4];
            #pragma unroll
            for (int i = 0; i < 4; i++) {
                af[i]  = *(const bf16x8*)&As[(wm + i * 16 + l15) * 64 + kk + lq * 8];
                bf_[i] = *(const bf16x8*)&Bs[(wn + i * 16 + l15) * 64 + kk + lq * 8];
            }
            #pragma unroll
            for (int i = 0; i < 4; i++)
                #pragma unroll
                for (int j = 0; j < 4; j++)
                    acc[i][j] = __builtin_amdgcn_mfma_f32_16x16x32_bf16(
                        af[i], bf_[j], acc[i][j], 0, 0, 0);
        }
        __syncthreads();
    }

    if (EPI == 0) {
        float* P = Cpart + (long)ks * M * 128;
        #pragma unroll
        for (int i = 0; i < 4; i++)
            #pragma unroll
            for (int j = 0; j < 4; j++) {
                const int col = wn + j * 16 + l15;
                #pragma unroll
                for (int r = 0; r < 4; r++) {
                    const int row = m0 + wm + i * 16 + lq * 4 + r;
                    if (row < M) P[(long)row * 128 + col] = acc[i][j][r];
                }
            }
    } else {
        #pragma unroll
        for (int j = 0; j < 4; j++) {
            const int col = wn + j * 16 + l15;
            const float bz = bias[col];
            #pragma unroll
            for (int i = 0; i < 4; i++)
                #pragma unroll
                for (int r = 0; r < 4; r++) {
                    const int row = m0 + wm + i * 16 + lq * 4 + r;
                    if (row < M)
                        Ot[(long)col * M + row] = f2bf((acc[i][j][r] + bz) * rowscale[row]);
                }
        }
    }
}

// ---------------------------------------------------------------------------
// H fp32 [NN x NE] -> Hb bf16 [NN x NE] and HbT bf16 [NE x NN] (tiled 64x64)
// ---------------------------------------------------------------------------
__global__ __launch_bounds__(256)
void cvt_trans_kernel(const float* __restrict__ H, short* __restrict__ Hb,
                      short* __restrict__ HbT)
{
    __shared__ short T[64 * 68];            // [n][e], stride 68 (136B)
    const int eb = blockIdx.x % (NE / 64);
    const int nb = blockIdx.x / (NE / 64);
    const int e0 = eb * 64, n0 = nb * 64;
    const int t = threadIdx.x;
    {
        const int c4 = (t & 15) * 4;        // e offset
        const int r  = t >> 4;              // 0..15
        #pragma unroll
        for (int p = 0; p < 4; p++) {
            const int n = r + p * 16;
            const long gn = n0 + n;
            floatx4 v = {0.f, 0.f, 0.f, 0.f};
            if (gn < NN) v = *(const floatx4*)(H + gn * NE + e0 + c4);
            short4v s;
            s[0] = f2bf(v[0]); s[1] = f2bf(v[1]); s[2] = f2bf(v[2]); s[3] = f2bf(v[3]);
            if (gn < NN) *(short4v*)(Hb + gn * NE + e0 + c4) = s;
            *(short4v*)&T[n * 68 + c4] = s;
        }
    }
    __syncthreads();
    {
        const int n4 = (t & 15) * 4;        // n offset
        const int el = t >> 4;              // 0..15
        #pragma unroll
        for (int p = 0; p < 4; p++) {
            const int e = el + p * 16;
            short4v s;
            #pragma unroll
            for (int j = 0; j < 4; j++) s[j] = T[(n4 + j) * 68 + e];
            if (n0 + n4 < NN)
                *(short4v*)&HbT[(long)(e0 + e) * NN + n0 + n4] = s;
        }
    }
}

// X0[n][d] = emb[n] . Wt[tid[n]][:,d] + bt[tid[n]][d]; writes fp32 + bf16
__global__ void x0_kernel(const float* __restrict__ emb, const float* __restrict__ Wt,
                          const float* __restrict__ bt, const int* __restrict__ tids,
                          float* __restrict__ X0f, short* __restrict__ X0b)
{
    const int n = blockIdx.x;
    const int d = threadIdx.x;
    __shared__ float er[128];
    er[d] = emb[(long)n * 128 + d];
    __syncthreads();
    const int tt = tids[n];
    const float* W = Wt + (long)tt * 16384;
    float acc = bt[tt * 128 + d];
    #pragma unroll 8
    for (int k = 0; k < 128; k++)
        acc = fmaf(er[k], W[k * 128 + d], acc);
    X0f[(long)n * 128 + d] = acc;
    X0b[(long)n * 128 + d] = f2bf(acc);
}

// W1bt[n][k] = bf16(W1[k][n]), same for W2; softmax(fusion_w) -> w[0..2]
__global__ void prep_kernel(const float* __restrict__ W1, const float* __restrict__ W2,
                            const float* __restrict__ fw,
                            short* __restrict__ W1bt, short* __restrict__ W2bt,
                            float* __restrict__ w)
{
    const int i = blockIdx.x * 256 + threadIdx.x;
    if (i < 16384) {
        const int n = i >> 7, k = i & 127;
        W1bt[i] = f2bf(W1[k * 128 + n]);
        W2bt[i] = f2bf(W2[k * 128 + n]);
    }
    if (i == 0) {
        float a = fw[0], b = fw[1], c = fw[2];
        float m = fmaxf(a, fmaxf(b, c));
        float ea = __expf(a - m), eb = __expf(b - m), ec = __expf(c - m);
        float s = ea + eb + ec;
        w[0] = ea / s; w[1] = eb / s; w[2] = ec / s;
    }
}

// mbT[d][e] = bf16(de[e] * sum_{s<8} P1[s][e][d])   (transpose via LDS)
__global__ __launch_bounds__(256)
void redE_kernel(const float* __restrict__ P1, const float* __restrict__ de,
                 short* __restrict__ mbT)
{
    __shared__ short T[64 * 132];           // [e][d], 264B stride
    const int e0 = blockIdx.x * 64;
    const int t = threadIdx.x;
    {
        const int d4 = (t & 31) * 4;
        const int el = t >> 5;              // 0..7
        #pragma unroll
        for (int p = 0; p < 8; p++) {
            const int e = el + p * 8;
            const long base = (long)(e0 + e) * 128 + d4;
            floatx4 s = {0.f, 0.f, 0.f, 0.f};
            #pragma unroll
            for (int sp = 0; sp < 8; sp++)
                s += *(const floatx4*)(P1 + (long)sp * NE * 128 + base);
            const float sc = de[e0 + e];
            short4v o;
            #pragma unroll
            for (int j = 0; j < 4; j++) o[j] = f2bf(s[j] * sc);
            *(short4v*)&T[e * 132 + d4] = o;
        }
    }
    __syncthreads();
    {
        const int e4 = (t & 15) * 4;
        const int dl = t >> 4;              // 0..15
        #pragma unroll
        for (int p = 0; p < 8; p++) {
            const int d = dl + p * 16;
            short4v o;
            #pragma unroll
            for (int j = 0; j < 4; j++) o[j] = T[(e4 + j) * 132 + d];
            *(short4v*)&mbT[(long)d * NE + e0 + e4] = o;
        }
    }
}

// X1f = dv * sum_{s<4} P2[s]; X1b = bf16(X1f)
__global__ void redN_kernel(const float* __restrict__ P2, const float* __restrict__ dv,
                            float* __restrict__ Xf, short* __restrict__ Xb)
{
    const long i = (long)blockIdx.x * 256 + threadIdx.x;
    const long b = i * 4;
    if (b >= (long)NN * 128) return;
    floatx4 s = {0.f, 0.f, 0.f, 0.f};
    #pragma unroll
    for (int sp = 0; sp < 4; sp++)
        s += *(const floatx4*)(P2 + (long)sp * NN * 128 + b);
    const float sc = dv[b >> 7];
    s *= sc;
    *(floatx4*)(Xf + b) = s;
    short4v o;
    #pragma unroll
    for (int j = 0; j < 4; j++) o[j] = f2bf(s[j]);
    *(short4v*)(Xb + b) = o;
}

// out = w0*X0f + w1*X1f + w2*(dv * sum_{s<4} P2[s])
__global__ void fusion_kernel(const float* __restrict__ P2, const float* __restrict__ X0f,
                              const float* __restrict__ X1f, const float* __restrict__ dv,
                              const float* __restrict__ w, float* __restrict__ out)
{
    const long i = (long)blockIdx.x * 256 + threadIdx.x;
    const long b = i * 4;
    if (b >= (long)NN * 128) return;
    floatx4 s = {0.f, 0.f, 0.f, 0.f};
    #pragma unroll
    for (int sp = 0; sp < 4; sp++)
        s += *(const floatx4*)(P2 + (long)sp * NN * 128 + b);
    const float w0 = w[0], w1 = w[1], w2 = w[2];
    const float sc = dv[b >> 7];
    const floatx4 a = *(const floatx4*)(X0f + b);
    const floatx4 c = *(const floatx4*)(X1f + b);
    floatx4 o;
    #pragma unroll
    for (int j = 0; j < 4; j++) o[j] = w0 * a[j] + w1 * c[j] + w2 * (sc * s[j]);
    *(floatx4*)(out + b) = o;
}

// ---------------------------------------------------------------------------
extern "C" void kernel_launch(void* const* d_in, const int* in_sizes, int n_in,
                              void* d_out, int out_size, void* d_ws, size_t ws_size,
                              hipStream_t stream)
{
    const float* emb = (const float*)d_in[0];
    const float* Wt  = (const float*)d_in[1];
    const float* bt  = (const float*)d_in[2];
    const float* W1  = (const float*)d_in[3];
    const float* b1  = (const float*)d_in[4];
    const float* W2  = (const float*)d_in[5];
    const float* b2  = (const float*)d_in[6];
    const float* fw  = (const float*)d_in[7];
    const float* H   = (const float*)d_in[8];
    const float* dv  = (const float*)d_in[9];
    const float* de  = (const float*)d_in[10];
    const int*   tids= (const int*)d_in[11];
    float* out = (float*)d_out;

    // workspace layout (A-operands may be over-read by <=95 rows; each A buffer
    // is followed by >=2.6MB of other ws, so over-reads stay mapped)
    char* p = (char*)d_ws;
    short* Hb   = (short*)p;  p += (size_t)NN * NE * 2;       // 320 MB
    short* HbT  = (short*)p;  p += (size_t)NE * NN * 2;       // 320 MB
    float* P1   = (float*)p;  p += (size_t)8 * NE * 128 * 4;  // 32.8 MB
    float* P2   = (float*)p;  p += (size_t)4 * NN * 128 * 4;  // 41 MB
    float* X0f  = (float*)p;  p += (size_t)NN * 128 * 4;
    float* X1f  = (float*)p;  p += (size_t)NN * 128 * 4;
    short* Yt   = (short*)p;  p += (size_t)128 * NN * 2;
    short* X0b  = (short*)p;  p += (size_t)NN * 128 * 2;
    short* X1b  = (short*)p;  p += (size_t)NN * 128 * 2;
    short* mbT  = (short*)p;  p += (size_t)128 * NE * 2;
    short* W1bt = (short*)p;  p += 16384 * 2;
    short* W2bt = (short*)p;  p += 16384 * 2;
    float* w    = (float*)p;  p += 4 * 4;
    p += (1 << 22);                                           // overrun pad
    if ((size_t)(p - (char*)d_ws) > ws_size) return;

    prep_kernel<<<64, 256, 0, stream>>>(W1, W2, fw, W1bt, W2bt, w);
    cvt_trans_kernel<<<(NE / 64) * ((NN + 63) / 64), 256, 0, stream>>>(H, Hb, HbT);
    x0_kernel<<<NN, 128, 0, stream>>>(emb, Wt, bt, tids, X0f, X0b);

    // ---------------- layer 1 ----------------
    gemm_bt<1><<<157, 256, 0, stream>>>(X0b, W1bt, nullptr, Yt, b1, dv, NN, 128, 157, 128);
    gemm_bt<0><<<63 * 8, 256, 0, stream>>>(HbT, Yt, P1, nullptr, nullptr, nullptr,
                                           NE, NN, 63, 2560);
    redE_kernel<<<NE / 64, 256, 0, stream>>>(P1, de, mbT);
    gemm_bt<0><<<157 * 4, 256, 0, stream>>>(Hb, mbT, P2, nullptr, nullptr, nullptr,
                                            NN, NE, 157, 2048);
    redN_kernel<<<2500, 256, 0, stream>>>(P2, dv, X1f, X1b);

    // ---------------- layer 2 ----------------
    gemm_bt<1><<<157, 256, 0, stream>>>(X1b, W2bt, nullptr, Yt, b2, dv, NN, 128, 157, 128);
    gemm_bt<0><<<63 * 8, 256, 0, stream>>>(HbT, Yt, P1, nullptr, nullptr, nullptr,
                                           NE, NN, 63, 2560);
    redE_kernel<<<NE / 64, 256, 0, stream>>>(P1, de, mbT);
    gemm_bt<0><<<157 * 4, 256, 0, stream>>>(Hb, mbT, P2, nullptr, nullptr, nullptr,
                                            NN, NE, 157, 2048);
    fusion_kernel<<<2500, 256, 0, stream>>>(P2, X0f, X1f, dv, w, out);
}